// Round 2
// baseline (46.847 us; speedup 1.0000x reference)
//
#include <hip/hip_runtime.h>

// PlaylistEmbedding: out[b, :] = sum_n values[b,n] * w[indices[b,n], :] + bias
// B=16384, NNZ=200, EMB=32, fp32, indices int32.
//
// One wave (64 lanes) per output row. Lane decomposition:
//   c      = lane & 7   -> float4 chunk of the 32-wide embedding
//   n_slot = lane >> 3  -> which of 8 concurrent gather streams over NNZ
// Each lane accumulates over n = n_slot + 8k (k=0..24), then shfl_xor
// reduction over n_slot (masks 8,16,32). No LDS -> high occupancy; 8 gather
// streams per row hide L2/L3/HBM gather latency.

constexpr int NNZ = 200;
constexpr int THREADS = 256;   // 4 waves/block -> 4 rows/block

__global__ __launch_bounds__(THREADS, 6) void playlist_embedding_kernel(
    const int* __restrict__ indices,     // [B, NNZ]
    const float* __restrict__ values,    // [B, NNZ]
    const float* __restrict__ w,         // [VOCAB, 32]
    const float* __restrict__ bias,      // [32]
    float* __restrict__ out)             // [B, 32]
{
    const int tid    = threadIdx.x;
    const int wave   = tid >> 6;         // 0..3
    const int lane   = tid & 63;
    const int n_slot = lane >> 3;        // 0..7
    const int c      = lane & 7;         // 0..7

    const int row = blockIdx.x * 4 + wave;

    const int*   __restrict__ ri = indices + (size_t)row * NNZ;
    const float* __restrict__ rv = values  + (size_t)row * NNZ;
    const float4* __restrict__ w4 = (const float4*)w;

    float ax = 0.f, ay = 0.f, az = 0.f, aw = 0.f;

    #pragma unroll 5
    for (int k = 0; k < NNZ / 8; ++k) {          // 25 iters
        const int n = n_slot + (k << 3);
        const int   u = ri[n];                   // broadcast within 8-lane c-group
        const float v = rv[n];
        const float4 wv = w4[(size_t)u * 8 + c]; // 16B of the row's 128B line
        ax += v * wv.x;
        ay += v * wv.y;
        az += v * wv.z;
        aw += v * wv.w;
    }

    // Reduce across the 8 n_slots (lane strides of 8, 16, 32)
    #pragma unroll
    for (int mask = 8; mask <= 32; mask <<= 1) {
        ax += __shfl_xor(ax, mask);
        ay += __shfl_xor(ay, mask);
        az += __shfl_xor(az, mask);
        aw += __shfl_xor(aw, mask);
    }

    if (n_slot == 0) {
        const float4 bias4 = ((const float4*)bias)[c];
        float4 o;
        o.x = ax + bias4.x;
        o.y = ay + bias4.y;
        o.z = az + bias4.z;
        o.w = aw + bias4.w;
        ((float4*)out)[(size_t)row * 8 + c] = o;
    }
}

extern "C" void kernel_launch(void* const* d_in, const int* in_sizes, int n_in,
                              void* d_out, int out_size, void* d_ws, size_t ws_size,
                              hipStream_t stream) {
    const int*   indices = (const int*)d_in[0];    // [16384, 200]
    const float* values  = (const float*)d_in[1];  // [16384, 200]
    const float* w       = (const float*)d_in[2];  // [81616, 32]
    const float* bias    = (const float*)d_in[3];  // [32]
    float* out = (float*)d_out;                    // [16384, 32]

    const int B = in_sizes[0] / NNZ;               // 16384
    const int grid = B / 4;                        // 4096 blocks, 4 rows each

    playlist_embedding_kernel<<<grid, THREADS, 0, stream>>>(
        indices, values, w, bias, out);
}

// Round 3
// 45.637 us; speedup vs baseline: 1.0265x; 1.0265x over previous
//
#include <hip/hip_runtime.h>

// PlaylistEmbedding: out[b,:] = sum_n values[b,n] * w[indices[b,n],:] + bias
// B=16384, NNZ=200, EMB=32, fp32, indices int32.
//
// One wave per output row. lane = s*8 + c:
//   c in [0,8) -> float4 chunk of the 32-wide embedding (8 consecutive lanes
//                 cover one 128B w row -> perfect line coalescing)
//   s in [0,8) -> which contiguous nnz block: stage k covers n = 32k+4s+{0..3}
// Per stage, each lane loads ONE int4 of indices + ONE float4 of values
// (16B aligned: row base = 800B*row, offsets 128k+16s) and issues 4 float4
// gathers. 3-slot rotating software pipeline (fully unrolled, compile-time
// slot indices) keeps idx(k+2) + gathers(k+1) in flight while FMAing stage k.
// Stage 6 is the 8-element tail (only s<2 carry real values; others get v=0).

constexpr int NNZ = 200;
constexpr int THREADS = 256;
constexpr int ROWS_PER_BLOCK = 4;   // 4 waves/block
constexpr int NSTAGE = 7;           // 6 full 32-nnz stages + 1 tail stage

__global__ __launch_bounds__(THREADS, 4) void playlist_embedding_kernel(
    const int* __restrict__ indices,     // [B, NNZ]
    const float* __restrict__ values,    // [B, NNZ]
    const float* __restrict__ w,         // [VOCAB, 32]
    const float* __restrict__ bias,      // [32]
    float* __restrict__ out)             // [B, 32]
{
    const int tid  = threadIdx.x;
    const int wave = tid >> 6;
    const int lane = tid & 63;
    const int s    = lane >> 3;          // nnz-block slot 0..7
    const int c    = lane & 7;           // float4 chunk 0..7

    const int row = blockIdx.x * ROWS_PER_BLOCK + wave;

    const int*   __restrict__ ri = indices + (size_t)row * NNZ;
    const float* __restrict__ rv = values  + (size_t)row * NNZ;
    const float4* __restrict__ w4 = (const float4*)w;

    int4   id[3];
    float4 vl[3];
    float4 gb[3][4];
    float ax = 0.f, ay = 0.f, az = 0.f, aw = 0.f;

    auto loadiv = [&](int slot, int k) {
        int off;
        if (k < 6) off = 32 * k + 4 * s;
        else       off = 192 + ((s < 2) ? 4 * s : 0);   // tail: clamp s>=2
        id[slot] = *(const int4*)(ri + off);
        float4 t = *(const float4*)(rv + off);
        if (k == 6 && s >= 2) { t.x = 0.f; t.y = 0.f; t.z = 0.f; t.w = 0.f; }
        vl[slot] = t;
    };
    auto gather = [&](int slot) {
        gb[slot][0] = w4[id[slot].x * 8 + c];
        gb[slot][1] = w4[id[slot].y * 8 + c];
        gb[slot][2] = w4[id[slot].z * 8 + c];
        gb[slot][3] = w4[id[slot].w * 8 + c];
    };
    auto fmas = [&](int slot) {
        const float4 v = vl[slot];
        ax += v.x * gb[slot][0].x; ay += v.x * gb[slot][0].y;
        az += v.x * gb[slot][0].z; aw += v.x * gb[slot][0].w;
        ax += v.y * gb[slot][1].x; ay += v.y * gb[slot][1].y;
        az += v.y * gb[slot][1].z; aw += v.y * gb[slot][1].w;
        ax += v.z * gb[slot][2].x; ay += v.z * gb[slot][2].y;
        az += v.z * gb[slot][2].z; aw += v.z * gb[slot][2].w;
        ax += v.w * gb[slot][3].x; ay += v.w * gb[slot][3].y;
        az += v.w * gb[slot][3].z; aw += v.w * gb[slot][3].w;
    };

    // Pipeline prologue
    loadiv(0, 0);
    loadiv(1, 1);
    gather(0);

    // Steady state: load idx(k+2) || gather(k+1) || fma(k). Fully unrolled so
    // every array index is a compile-time constant (no scratch).
    #pragma unroll
    for (int k = 0; k < NSTAGE; ++k) {
        if (k + 2 < NSTAGE) loadiv((k + 2) % 3, k + 2);
        if (k + 1 < NSTAGE) gather((k + 1) % 3);
        fmas(k % 3);
    }

    // Reduce across the 8 s-slots (lane bits 3..5)
    #pragma unroll
    for (int m = 8; m <= 32; m <<= 1) {
        ax += __shfl_xor(ax, m);
        ay += __shfl_xor(ay, m);
        az += __shfl_xor(az, m);
        aw += __shfl_xor(aw, m);
    }

    if (s == 0) {
        const float4 bias4 = ((const float4*)bias)[c];
        float4 o;
        o.x = ax + bias4.x;
        o.y = ay + bias4.y;
        o.z = az + bias4.z;
        o.w = aw + bias4.w;
        ((float4*)out)[(size_t)row * 8 + c] = o;
    }
}

extern "C" void kernel_launch(void* const* d_in, const int* in_sizes, int n_in,
                              void* d_out, int out_size, void* d_ws, size_t ws_size,
                              hipStream_t stream) {
    const int*   indices = (const int*)d_in[0];    // [16384, 200]
    const float* values  = (const float*)d_in[1];  // [16384, 200]
    const float* w       = (const float*)d_in[2];  // [81616, 32]
    const float* bias    = (const float*)d_in[3];  // [32]
    float* out = (float*)d_out;                    // [16384, 32]

    const int B = in_sizes[0] / NNZ;               // 16384
    const int grid = B / ROWS_PER_BLOCK;           // 4096

    playlist_embedding_kernel<<<grid, THREADS, 0, stream>>>(
        indices, values, w, bias, out);
}

// Round 5
// 45.489 us; speedup vs baseline: 1.0298x; 1.0033x over previous
//
#include <hip/hip_runtime.h>

// PlaylistEmbedding: out[b,:] = sum_n values[b,n] * w[indices[b,n],:] + bias
// B=16384, NNZ=200, EMB=32, fp32, indices int32.
//
// One wave per row; lane = s*8 + c (s = nnz-block slot, c = float4 chunk).
// Stage k covers n = 32k + 4s + {0..3}; stage 6 is the 8-wide tail (s<2).
//
// HAND-PIPELINED GATHERS: rounds 1-3 show the compiler collapses every
// source-level pipeline (VGPR 24/36 -> ~1 gather in flight per wave). Here
// w-gathers are asm-volatile global_load_dwordx4; pipeline depth is enforced
// with hand-counted `s_waitcnt vmcnt(4)` + `sched_barrier(0)` (rule #18:
// the sched_barrier stops hipcc from hoisting register-only FMAs above the
// waitcnt; tied "+v" operands are NOT supported on gfx950 inline asm).
// vmcnt protocol: all ordinary vmem (idx/val preloads) drained by vmcnt(0)
// before the pipeline; bias/store held after it by memory clobbers, so the
// only interior vmem is our 28 asm gathers and the counts are exact.

constexpr int NNZ = 200;
constexpr int THREADS = 256;

__global__ __launch_bounds__(THREADS, 4) void playlist_embedding_kernel(
    const int* __restrict__ indices,     // [B, NNZ]
    const float* __restrict__ values,    // [B, NNZ]
    const float* __restrict__ w,         // [VOCAB, 32]
    const float* __restrict__ bias,      // [32]
    float* __restrict__ out)             // [B, 32]
{
    const int tid  = threadIdx.x;
    const int wave = tid >> 6;
    const int lane = tid & 63;
    const int s    = lane >> 3;          // 0..7
    const int c    = lane & 7;           // 0..7
    const int row  = blockIdx.x * 4 + wave;

    const int*   __restrict__ ri = indices + (size_t)row * NNZ;
    const float* __restrict__ rv = values  + (size_t)row * NNZ;
    const float4* __restrict__ w4 = (const float4*)w;

    // ---- Preload all indices/values for this row (14 coalesced 16B loads) ----
    int4   id[7];
    float4 vl[7];
#pragma unroll
    for (int k = 0; k < 7; ++k) {
        const int off = (k < 6) ? (32 * k + 4 * s)
                                : (192 + ((s < 2) ? 4 * s : 0));  // tail clamp
        id[k] = *(const int4*)(ri + off);
        float4 t = *(const float4*)(rv + off);
        if (k == 6 && s >= 2) { t.x = 0.f; t.y = 0.f; t.z = 0.f; t.w = 0.f; }
        vl[k] = t;
    }

    // Drain ALL ordinary vmem so the asm pipeline's vmcnt counts are exact.
    asm volatile("s_waitcnt vmcnt(0)" ::: "memory");
    __builtin_amdgcn_sched_barrier(0);

    float4 A0, A1, A2, A3, B0, B1, B2, B3;
    float ax = 0.f, ay = 0.f, az = 0.f, aw = 0.f;

#define GATHER(G0, G1, G2, G3, K) do {                                         \
    const float4* a0_ = w4 + ((long)id[K].x * 8 + c);                          \
    const float4* a1_ = w4 + ((long)id[K].y * 8 + c);                          \
    const float4* a2_ = w4 + ((long)id[K].z * 8 + c);                          \
    const float4* a3_ = w4 + ((long)id[K].w * 8 + c);                          \
    asm volatile("global_load_dwordx4 %0, %1, off" : "=v"(G0) : "v"(a0_));     \
    asm volatile("global_load_dwordx4 %0, %1, off" : "=v"(G1) : "v"(a1_));     \
    asm volatile("global_load_dwordx4 %0, %1, off" : "=v"(G2) : "v"(a2_));     \
    asm volatile("global_load_dwordx4 %0, %1, off" : "=v"(G3) : "v"(a3_));     \
} while (0)

#define FMAS(G0, G1, G2, G3, K) do {                                           \
    const float4 v_ = vl[K];                                                   \
    ax += v_.x * G0.x; ay += v_.x * G0.y; az += v_.x * G0.z; aw += v_.x * G0.w;\
    ax += v_.y * G1.x; ay += v_.y * G1.y; az += v_.y * G1.z; aw += v_.y * G1.w;\
    ax += v_.z * G2.x; ay += v_.z * G2.y; az += v_.z * G2.z; aw += v_.z * G2.w;\
    ax += v_.w * G3.x; ay += v_.w * G3.y; az += v_.w * G3.z; aw += v_.w * G3.w;\
} while (0)

#define WAIT4() do {                                                           \
    asm volatile("s_waitcnt vmcnt(4)" ::: "memory");                           \
    __builtin_amdgcn_sched_barrier(0);                                         \
} while (0)

#define WAIT0() do {                                                           \
    asm volatile("s_waitcnt vmcnt(0)" ::: "memory");                           \
    __builtin_amdgcn_sched_barrier(0);                                         \
} while (0)

    // 2-deep pipeline: stage k+1's gathers are in flight through stage k's FMAs.
    GATHER(A0, A1, A2, A3, 0);

    GATHER(B0, B1, B2, B3, 1); WAIT4(); FMAS(A0, A1, A2, A3, 0);
    GATHER(A0, A1, A2, A3, 2); WAIT4(); FMAS(B0, B1, B2, B3, 1);
    GATHER(B0, B1, B2, B3, 3); WAIT4(); FMAS(A0, A1, A2, A3, 2);
    GATHER(A0, A1, A2, A3, 4); WAIT4(); FMAS(B0, B1, B2, B3, 3);
    GATHER(B0, B1, B2, B3, 5); WAIT4(); FMAS(A0, A1, A2, A3, 4);
    GATHER(A0, A1, A2, A3, 6); WAIT4(); FMAS(B0, B1, B2, B3, 5);
                               WAIT0(); FMAS(A0, A1, A2, A3, 6);

#undef GATHER
#undef FMAS
#undef WAIT4
#undef WAIT0

    // Keep bias load / out store from being hoisted into the asm region.
    asm volatile("" ::: "memory");

    // Reduce across the 8 s-slots (lane bits 3..5)
#pragma unroll
    for (int m = 8; m <= 32; m <<= 1) {
        ax += __shfl_xor(ax, m);
        ay += __shfl_xor(ay, m);
        az += __shfl_xor(az, m);
        aw += __shfl_xor(aw, m);
    }

    if (s == 0) {
        const float4 bias4 = ((const float4*)bias)[c];
        float4 o;
        o.x = ax + bias4.x;
        o.y = ay + bias4.y;
        o.z = az + bias4.z;
        o.w = aw + bias4.w;
        ((float4*)out)[(size_t)row * 8 + c] = o;
    }
}

extern "C" void kernel_launch(void* const* d_in, const int* in_sizes, int n_in,
                              void* d_out, int out_size, void* d_ws, size_t ws_size,
                              hipStream_t stream) {
    const int*   indices = (const int*)d_in[0];    // [16384, 200]
    const float* values  = (const float*)d_in[1];  // [16384, 200]
    const float* w       = (const float*)d_in[2];  // [81616, 32]
    const float* bias    = (const float*)d_in[3];  // [32]
    float* out = (float*)d_out;                    // [16384, 32]

    const int B = in_sizes[0] / NNZ;               // 16384
    const int grid = B / 4;                        // 4096 blocks, 4 rows each

    playlist_embedding_kernel<<<grid, THREADS, 0, stream>>>(
        indices, values, w, bias, out);
}